// Round 1
// baseline (474.012 us; speedup 1.0000x reference)
//
#include <hip/hip_runtime.h>
#include <cstdint>

#define SEQ 512
#define BATCH 2048
#define HID 50
#define BB 4              // batches per block
#define NTHR 512          // 8 waves: 0-3 = L1 group, 4-7 = L2 group
#define NBLK (BATCH / BB) // 512 blocks -> 2 per CU (independent barriers!)
#define NT 13             // gate-row tiles of 16 (200 -> 208, permuted rows)
#define S1H 80            // u1 stride halves: 40 dwords === 8 (mod 32) -> 2-way banks (free)
#define S2H 144           // u2 stride halves: 72 dwords === 8 (mod 32) -> 2-way banks (free)

typedef _Float16 f16;
typedef _Float16 v8h __attribute__((ext_vector_type(8)));
typedef float    v4f __attribute__((ext_vector_type(4)));

#if __has_builtin(__builtin_amdgcn_exp2f)
#define EXP2F(x) __builtin_amdgcn_exp2f(x)
#else
#define EXP2F(x) exp2f(x)
#endif
#define RCPF(x) __builtin_amdgcn_rcpf(x)
#define LOG2E 1.44269504f
#define MFMA(A,B,C) __builtin_amdgcn_mfma_f32_16x16x32_f16(A, B, C, 0, 0, 0)

// Row permutation (validated R5-R11): tile tt, in-tile row rho -> orig W row
// (rho%4)*50 + tt*4 + rho/4.  C layout (col=lane&15, row=(lane>>4)*4+reg)
// puts [i,f,g,o] of unit uc=tt*4+q, batch col&3 in one lane's 4 C-regs.
// BB=4 packing: B cols carry batch mb&3 in 4 copies; copy=mb>>2 selects one of
// FOUR accumulators a0..a3 = tiles {wa, wa+4, wa+8, wa+12} -> 4 waves/layer
// cover all 13 tiles. Biases ride a constant-1.0 u-column (k=54 / k=100);
// gate rows pre-scaled (i,f,o: -log2e; g: +2log2e) so update uses raw exp2.

__global__ __launch_bounds__(NTHR, 4) void lstm2_fused(
    const float* __restrict__ x,
    const float* __restrict__ w_ih1, const float* __restrict__ w_hh1,
    const float* __restrict__ b_ih1, const float* __restrict__ b_hh1,
    const float* __restrict__ w_ih2, const float* __restrict__ w_hh2,
    const float* __restrict__ b_ih2, const float* __restrict__ b_hh2,
    const float* __restrict__ w_fc, const float* __restrict__ b_fc,
    float* __restrict__ out)
{
    __shared__ __align__(16) f16 u1h[2][BB * S1H];
    __shared__ __align__(16) f16 u2h[2][BB * S2H];
    __shared__ float fcw[2][64];

    const int tid  = threadIdx.x;
    const int wv   = tid >> 6;        // 0..7
    const int lane = tid & 63;
    const int mb   = lane & 15;       // A-row-in-tile | C col
    const int q    = lane >> 4;       // quad
    const int bbase = blockIdx.x * BB;

    const bool grpB = (wv >= 4);              // waves 4-7: L2
    const int  wa   = grpB ? (7 - wv) : wv;   // 0..3 (reversed for SIMD balance)

    // ---- per-lane packed update identity ----
    const int  copy   = mb >> 2;              // accumulator / tile selector
    const int  myt    = wa + 4 * copy;
    const int  u_me   = myt * 4 + q;
    const bool valid_upd = (myt < NT) && (u_me < HID);
    const int  b_me   = mb & 3;       // batch: B-load row AND update identity

    // gate scale for this lane's A-fragment rows (gate = mb&3)
    const int   gidx = mb & 3;
    const float sc   = (gidx == 2) ? (2.0f * LOG2E) : (-LOG2E);

    // ---- weight-stationary A fragments (scaled, bias column) ----
    v8h Af[4][4];                     // [tile-copy][ktile]; L1 uses kt 0..1, L2 kt 0..3
#pragma unroll
    for (int c = 0; c < 4; ++c) {
        const int tt = wa + 4 * c;
        const bool tv = (tt < NT);
        const int ru = tt * 4 + (mb >> 2);
        const bool rv = tv && (ru < HID);
        const int R = gidx * HID + ru;       // original gate-major W row
        if (!grpB) {
#pragma unroll
            for (int kt = 0; kt < 2; ++kt) {
                v8h f;
#pragma unroll
                for (int j = 0; j < 8; ++j) {
                    const int kk = kt * 32 + q * 8 + j;
                    float v = 0.0f;
                    if (rv) {
                        if (kk < 4) v = w_ih1[R * 4 + kk];
                        else if (kk < 54) v = w_hh1[R * HID + (kk - 4)];
                        else if (kk == 54) v = b_ih1[R] + b_hh1[R];
                    }
                    f[j] = (f16)(v * sc);
                }
                Af[c][kt] = f;
            }
        } else {
#pragma unroll
            for (int kt = 0; kt < 4; ++kt) {
                v8h f;
#pragma unroll
                for (int j = 0; j < 8; ++j) {
                    const int kk = kt * 32 + q * 8 + j;
                    float v = 0.0f;
                    if (rv) {
                        if (kk < HID) v = w_ih2[R * HID + kk];
                        else if (kk < 2 * HID) v = w_hh2[R * HID + (kk - HID)];
                        else if (kk == 100) v = b_ih2[R] + b_hh2[R];
                    }
                    f[j] = (f16)(v * sc);
                }
                Af[c][kt] = f;
            }
        }
    }
    const float wfc_me = (grpB && valid_upd) ? w_fc[u_me] : 0.0f;
    const float bfc = b_fc[0];
    float c_me = 0.0f;

    // ---- LDS init ----
    for (int idx = tid; idx < 2 * BB * S1H; idx += NTHR) ((f16*)u1h)[idx] = (f16)0.0f;
    for (int idx = tid; idx < 2 * BB * S2H; idx += NTHR) ((f16*)u2h)[idx] = (f16)0.0f;
    if (tid < 128) ((float*)fcw)[tid] = 0.0f;
    __syncthreads();
    if (tid < BB) {   // x(0) -> u1 parity 0
        const float4 x0 = *reinterpret_cast<const float4*>(x + (size_t)(bbase + tid) * 4);
        f16 p[4] = {(f16)x0.x, (f16)x0.y, (f16)x0.z, (f16)x0.w};
        *reinterpret_cast<uint2*>(&u1h[0][tid * S1H]) = *reinterpret_cast<uint2*>(p);
    }
    if (tid < 8) {    // constant-1 bias columns, both parities
        const int p = tid >> 2, b = tid & 3;
        u1h[p][b * S1H + 54] = (f16)1.0f;
        u2h[p][b * S2H + 100] = (f16)1.0f;
    }
    __syncthreads();

    // ---- hoisted per-parity LDS pointers ----
    const f16* u1rp[2] = {u1h[0] + b_me * S1H, u1h[1] + b_me * S1H};
    const f16* u2rp[2] = {u2h[0] + b_me * S2H, u2h[1] + b_me * S2H};
    f16* u1wp[2] = {u1h[0] + b_me * S1H, u1h[1] + b_me * S1H};
    f16* u2wp[2] = {u2h[0] + b_me * S2H, u2h[1] + b_me * S2H};

    // ---- superstep body (pr/pn become literals in the 2x-unrolled loop) ----
    auto body = [&](int s, int pr, int pn) __attribute__((always_inline)) {
        if (!grpB) {
            // ---------- x(s+1) prefetch (wave 1, light L1 wave) ----------
            float4 xr;
            if (wv == 1 && lane < BB) {
                const int tn = (s + 1 < SEQ) ? s + 1 : SEQ - 1;
                xr = *reinterpret_cast<const float4*>(
                    x + ((size_t)tn * BATCH + bbase + lane) * 4);
            }
            // ---------- L1 gates(t=s), packed lane-local update ----------
            const f16* u1r = u1rp[pr];
            const v8h B0 = *reinterpret_cast<const v8h*>(&u1r[q * 8]);
            const v8h B1 = *reinterpret_cast<const v8h*>(&u1r[32 + q * 8]);
            v4f a0 = {0.f, 0.f, 0.f, 0.f}, a1 = a0, a2 = a0, a3 = a0;
            a0 = MFMA(Af[0][0], B0, a0); a0 = MFMA(Af[0][1], B1, a0);
            a1 = MFMA(Af[1][0], B0, a1); a1 = MFMA(Af[1][1], B1, a1);
            a2 = MFMA(Af[2][0], B0, a2); a2 = MFMA(Af[2][1], B1, a2);
            if (wa == 0) {   // tile 12 is the only valid 4th tile
                a3 = MFMA(Af[3][0], B0, a3); a3 = MFMA(Af[3][1], B1, a3);
            }
            const bool lo2 = (mb & 8) == 0;   // copy bit1 clear -> a0/a1
            const bool lo1 = (mb & 4) == 0;   // copy bit0 clear -> even acc
            const float m0 = lo2 ? (lo1 ? a0[0] : a1[0]) : (lo1 ? a2[0] : a3[0]);
            const float m1 = lo2 ? (lo1 ? a0[1] : a1[1]) : (lo1 ? a2[1] : a3[1]);
            const float m2 = lo2 ? (lo1 ? a0[2] : a1[2]) : (lo1 ? a2[2] : a3[2]);
            const float m3 = lo2 ? (lo1 ? a0[3] : a1[3]) : (lo1 ? a2[3] : a3[3]);
            // pre-scaled gates: raw v_exp_f32
            const float A  = 1.0f + EXP2F(m0);
            const float F  = 1.0f + EXP2F(m1);
            const float Bv = 1.0f + EXP2F(m2);
            const float C  = 1.0f + EXP2F(m3);
            c_me = RCPF(F) * c_me + (Bv - 2.0f) * RCPF(A * Bv);
            const float D = 1.0f + EXP2F(c_me * (2.0f * LOG2E));
            const float h1v = (D - 2.0f) * RCPF(C * D);
            if (valid_upd) {
                u1wp[pn][4 + u_me] = (f16)h1v;
                u2wp[pr][u_me] = (f16)fmaxf(h1v, 0.0f);
            }
            // ---------- out store for t=s-2 (wave 3) ----------
            if (wv == 3 && s >= 2) {
                float v = fcw[pn][lane];            // idx = wa*4 + b (0..15)
                v += __shfl_xor(v, 4);
                v += __shfl_xor(v, 8);
                if (lane < BB) out[(size_t)(s - 2) * BATCH + bbase + lane] = v + bfc;
            }
            if (wv == 1 && lane < BB) {   // x(s+1) into next-parity u1
                f16 pk[4] = {(f16)xr.x, (f16)xr.y, (f16)xr.z, (f16)xr.w};
                *reinterpret_cast<uint2*>(&u1h[pn][lane * S1H]) = *reinterpret_cast<uint2*>(pk);
            }
        } else {
            // ---------- L2 gates(t=s-1), packed lane-local update + FC ----------
            const f16* u2r = u2rp[pn];
            const v8h C0 = *reinterpret_cast<const v8h*>(&u2r[q * 8]);
            const v8h C1 = *reinterpret_cast<const v8h*>(&u2r[32 + q * 8]);
            const v8h C2 = *reinterpret_cast<const v8h*>(&u2r[64 + q * 8]);
            const v8h C3 = *reinterpret_cast<const v8h*>(&u2r[96 + q * 8]);
            v4f a0 = {0.f, 0.f, 0.f, 0.f}, a1 = a0, a2 = a0, a3 = a0;
            a0 = MFMA(Af[0][0], C0, a0); a0 = MFMA(Af[0][1], C1, a0);
            a0 = MFMA(Af[0][2], C2, a0); a0 = MFMA(Af[0][3], C3, a0);
            a1 = MFMA(Af[1][0], C0, a1); a1 = MFMA(Af[1][1], C1, a1);
            a1 = MFMA(Af[1][2], C2, a1); a1 = MFMA(Af[1][3], C3, a1);
            a2 = MFMA(Af[2][0], C0, a2); a2 = MFMA(Af[2][1], C1, a2);
            a2 = MFMA(Af[2][2], C2, a2); a2 = MFMA(Af[2][3], C3, a2);
            if (wa == 0) {
                a3 = MFMA(Af[3][0], C0, a3); a3 = MFMA(Af[3][1], C1, a3);
                a3 = MFMA(Af[3][2], C2, a3); a3 = MFMA(Af[3][3], C3, a3);
            }
            const bool lo2 = (mb & 8) == 0;
            const bool lo1 = (mb & 4) == 0;
            const float m0 = lo2 ? (lo1 ? a0[0] : a1[0]) : (lo1 ? a2[0] : a3[0]);
            const float m1 = lo2 ? (lo1 ? a0[1] : a1[1]) : (lo1 ? a2[1] : a3[1]);
            const float m2 = lo2 ? (lo1 ? a0[2] : a1[2]) : (lo1 ? a2[2] : a3[2]);
            const float m3 = lo2 ? (lo1 ? a0[3] : a1[3]) : (lo1 ? a2[3] : a3[3]);
            const float A  = 1.0f + EXP2F(m0);
            const float F  = 1.0f + EXP2F(m1);
            const float Bv = 1.0f + EXP2F(m2);
            const float C  = 1.0f + EXP2F(m3);
            const float cn = RCPF(F) * c_me + (Bv - 2.0f) * RCPF(A * Bv);
            const float D = 1.0f + EXP2F(cn * (2.0f * LOG2E));
            const float h2v = (D - 2.0f) * RCPF(C * D);
            float p = 0.0f;
            if (s >= 1) {                       // t=s-1 valid
                c_me = cn;
                if (valid_upd) u2wp[pr][HID + u_me] = (f16)h2v;
                p = fmaxf(h2v, 0.0f) * wfc_me;  // wfc_me=0 on invalid lanes
            }
            p += __shfl_xor(p, 4);              // merge copy bit0
            p += __shfl_xor(p, 8);              // merge copy bit1
            p += __shfl_xor(p, 16);             // merge q bit0
            p += __shfl_xor(p, 32);             // merge q bit1
            if (s >= 1 && lane < BB) fcw[pr][wa * BB + lane] = p;
        }
        __syncthreads();   // the ONE barrier per superstep
    };

    // ---- pipelined supersteps, unrolled x2 (SEQ+2 = 514 is even) ----
#pragma unroll 1
    for (int s = 0; s < SEQ + 2; s += 2) {
        body(s, 0, 1);
        body(s + 1, 1, 0);
    }
}

extern "C" void kernel_launch(void* const* d_in, const int* in_sizes, int n_in,
                              void* d_out, int out_size, void* d_ws, size_t ws_size,
                              hipStream_t stream) {
    const float* X    = (const float*)d_in[0];
    const float* Wih1 = (const float*)d_in[1];
    const float* Whh1 = (const float*)d_in[2];
    const float* Bih1 = (const float*)d_in[3];
    const float* Bhh1 = (const float*)d_in[4];
    const float* Wih2 = (const float*)d_in[5];
    const float* Whh2 = (const float*)d_in[6];
    const float* Bih2 = (const float*)d_in[7];
    const float* Bhh2 = (const float*)d_in[8];
    const float* Wfc  = (const float*)d_in[9];
    const float* Bfc  = (const float*)d_in[10];
    float* out = (float*)d_out;

    lstm2_fused<<<dim3(NBLK), dim3(NTHR), 0, stream>>>(
        X, Wih1, Whh1, Bih1, Bhh1, Wih2, Whh2, Bih2, Bhh2, Wfc, Bfc, out);
}